// Round 4
// baseline (204.207 us; speedup 1.0000x reference)
//
#include <hip/hip_runtime.h>
#include <hip/hip_bf16.h>
#include <math.h>

// AdaptedEntropyBottleneck on MI355X.
// Shapes (fixed by setup_inputs): x [16,192,64,64] fp32, codebook [64] fp32 sorted,
// MLP params per channel: 1->3->3->3->3->1 with softplus(weights), tanh gates.
// Outputs: y_hat [N,C,H,W] then lik [N,C,H,W], concatenated flat in d_out (fp32).
//
// v4: FUSED. rocprof showed the standalone build_table kernel costs 74.6 us
// (48 workgroups, 2% occupancy, VALUBusy 1.9% -- pure latency, no hiding).
// Now each block owns one (n,c) slice (4096 elems) and builds its channel's
// 64-entry lik table in LDS itself: threads 0..127 compute one (k, side)
// chain each (identical per-side float op order as before -> same numerics),
// fully overlapped with the block's prefetched x loads. No d_ws, one launch.
// Main pass keeps v2's register-pivot searchsorted (3 LDS levels) and
// y_hat from tie-break registers.

#define CCH 192
#define KCB 64

typedef float f32x4 __attribute__((ext_vector_type(4)));

__device__ __forceinline__ float softplusf_(float x) {
    // jax.nn.softplus = logaddexp(x, 0) = max(x,0) + log1p(exp(-|x|))
    return fmaxf(x, 0.0f) + log1pf(expf(-fabsf(x)));
}
__device__ __forceinline__ float sigmoidf_(float x) {
    return 1.0f / (1.0f + expf(-x));
}

// One block = one (n,c) slice = 4096 elements = 1024 float4.
// 256 threads * 4 float4 each. c = blockIdx.x % 192 (block-uniform).
__global__ __launch_bounds__(256) void eb_fused(
        const float* __restrict__ x,
        const float* __restrict__ cb,
        const float* __restrict__ m0, const float* __restrict__ b0, const float* __restrict__ f0,
        const float* __restrict__ m1, const float* __restrict__ b1, const float* __restrict__ f1,
        const float* __restrict__ m2, const float* __restrict__ b2, const float* __restrict__ f2,
        const float* __restrict__ m3, const float* __restrict__ b3, const float* __restrict__ f3,
        const float* __restrict__ m4, const float* __restrict__ b4,
        float* __restrict__ out, int nvec) {
    __shared__ float s_cb[KCB];
    __shared__ float s_side[2 * KCB];   // [0:64) lower chain, [64:128) upper chain
    __shared__ float s_lik[KCB];

    const int tid  = threadIdx.x;
    const int bid  = blockIdx.x;
    const int c    = bid % CCH;
    const int base4 = bid * 1024;       // float4 base index of this slice

    // ---- prefetch: issue all 16 global loads now; they fly during table build
    const f32x4* xin = (const f32x4*)x;
    f32x4 xv0 = xin[base4 + 0 * 256 + tid];
    f32x4 xv1 = xin[base4 + 1 * 256 + tid];
    f32x4 xv2 = xin[base4 + 2 * 256 + tid];
    f32x4 xv3 = xin[base4 + 3 * 256 + tid];

    if (tid < 64) s_cb[tid] = cb[tid];

    // ---- table build: thread (tid<128) computes one (k, side) logits chain.
    // Per-side arithmetic identical (same accumulation order) to the old
    // build_table, so results match bit-for-bit up to compiler fma contraction.
    if (tid < 128) {
        const int k = tid & 63;
        const float v = cb[k] + ((tid < 64) ? -0.5f : 0.5f);

        float h0, h1, h2;
        {   // layer 0: (C,3,1) weights
            float z;
            z = softplusf_(m0[c * 3 + 0]) * v + b0[c * 3 + 0];
            z = z + tanhf(f0[c * 3 + 0]) * tanhf(z); h0 = z;
            z = softplusf_(m0[c * 3 + 1]) * v + b0[c * 3 + 1];
            z = z + tanhf(f0[c * 3 + 1]) * tanhf(z); h1 = z;
            z = softplusf_(m0[c * 3 + 2]) * v + b0[c * 3 + 2];
            z = z + tanhf(f0[c * 3 + 2]) * tanhf(z); h2 = z;
        }
        const float* Ms[3] = {m1, m2, m3};
        const float* Bs[3] = {b1, b2, b3};
        const float* Fs[3] = {f1, f2, f3};
        #pragma unroll
        for (int L = 0; L < 3; ++L) {
            const float* M = Ms[L];
            const float* B = Bs[L];
            const float* F = Fs[L];
            float n0, n1, n2;
            #pragma unroll
            for (int j = 0; j < 3; ++j) {
                float z = 0.0f;
                z += softplusf_(M[(c * 3 + j) * 3 + 0]) * h0;
                z += softplusf_(M[(c * 3 + j) * 3 + 1]) * h1;
                z += softplusf_(M[(c * 3 + j) * 3 + 2]) * h2;
                z += B[c * 3 + j];
                const float a = tanhf(F[c * 3 + j]);
                z = z + a * tanhf(z);
                if (j == 0) n0 = z; else if (j == 1) n1 = z; else n2 = z;
            }
            h0 = n0; h1 = n1; h2 = n2;
        }
        // layer 4: (C,1,3) weights, bias (C,1,1)
        float res = 0.0f;
        res += softplusf_(m4[c * 3 + 0]) * h0;
        res += softplusf_(m4[c * 3 + 1]) * h1;
        res += softplusf_(m4[c * 3 + 2]) * h2;
        res += b4[c];
        s_side[tid] = res;
    }
    __syncthreads();

    if (tid < 64) {
        const float lower = s_side[tid];
        const float upper = s_side[tid + 64];
        const float s  = lower + upper;
        const float sg = (s > 0.0f) ? -1.0f : ((s < 0.0f) ? 1.0f : 0.0f);
        float lik = fabsf(sigmoidf_(sg * upper) - sigmoidf_(sg * lower));
        s_lik[tid] = fmaxf(lik, 1e-9f);
    }
    __syncthreads();

    // ---- pivots for the first 3 binary-search levels (broadcast LDS reads)
    const float p32 = s_cb[32];
    const float p16 = s_cb[16], p48 = s_cb[48];
    const float p8  = s_cb[8],  p24 = s_cb[24], p40 = s_cb[40], p56 = s_cb[56];

    f32x4* yout = (f32x4*)out;
    #pragma unroll
    for (int half = 0; half < 4; ++half) {
        const f32x4 xv = (half == 0) ? xv0 : (half == 1) ? xv1
                        : (half == 2) ? xv2 : xv3;
        float xs[4] = {xv.x, xv.y, xv.z, xv.w};
        float ys[4], ls[4];
        #pragma unroll
        for (int q = 0; q < 4; ++q) {
            const float xx = xs[q];
            // searchsorted(cb, xx, side='left'): identical mid sequence to the
            // canonical 6-step loop, first 3 levels resolved from registers.
            const bool c1 = p32 < xx;
            const float v2 = c1 ? p48 : p16;
            const bool c2 = v2 < xx;
            const float v3 = c1 ? (c2 ? p56 : p40) : (c2 ? p24 : p8);
            const bool c3 = v3 < xx;

            int lo = c1 ? 33 : 0;
            int hi = c1 ? 64 : 32;
            const int m2i = c1 ? 48 : 16;
            lo = c2 ? (m2i + 1) : lo;
            hi = c2 ? hi : m2i;
            const int m3i = 8 + 16 * ((c1 ? 2 : 0) + (c2 ? 1 : 0));
            lo = c3 ? (m3i + 1) : lo;
            hi = c3 ? hi : m3i;

            #pragma unroll
            for (int it = 0; it < 3; ++it) {
                const int mid = (lo + hi) >> 1;
                if (s_cb[mid] < xx) lo = mid + 1; else hi = mid;
            }
            const int i  = lo;                       // insertion point in [0,64]
            int il = i - 1; il = (il < 0) ? 0 : il;
            const int ih = (i > 63) ? 63 : i;
            const float cl = s_cb[il];
            const float ch = s_cb[ih];
            // reference tie-break: pick hi iff |cb[hi]-x| < |cb[lo]-x| (strict)
            const bool pick_hi = fabsf(ch - xx) < fabsf(cl - xx);
            ys[q] = pick_hi ? ch : cl;               // y_hat from registers
            ls[q] = s_lik[pick_hi ? ih : il];
        }

        f32x4 yo;  yo.x  = ys[0]; yo.y  = ys[1]; yo.z  = ys[2]; yo.w  = ys[3];
        f32x4 lo4; lo4.x = ls[0]; lo4.y = ls[1]; lo4.z = ls[2]; lo4.w = ls[3];
        const int e4 = base4 + half * 256 + tid;
        yout[e4]        = yo;
        yout[nvec + e4] = lo4;
    }
}

extern "C" void kernel_launch(void* const* d_in, const int* in_sizes, int n_in,
                              void* d_out, int out_size, void* d_ws, size_t ws_size,
                              hipStream_t stream) {
    // setup_inputs dict order:
    // 0:x 1:codebook 2:m0 3:b0 4:f0 5:m1 6:b1 7:f1 8:m2 9:b2 10:f2
    // 11:m3 12:b3 13:f3 14:m4 15:b4
    const float* x  = (const float*)d_in[0];
    const float* cb = (const float*)d_in[1];
    const float* m0 = (const float*)d_in[2];
    const float* b0 = (const float*)d_in[3];
    const float* f0 = (const float*)d_in[4];
    const float* m1 = (const float*)d_in[5];
    const float* b1 = (const float*)d_in[6];
    const float* f1 = (const float*)d_in[7];
    const float* m2 = (const float*)d_in[8];
    const float* b2 = (const float*)d_in[9];
    const float* f2 = (const float*)d_in[10];
    const float* m3 = (const float*)d_in[11];
    const float* b3_ = (const float*)d_in[12];
    const float* f3 = (const float*)d_in[13];
    const float* m4 = (const float*)d_in[14];
    const float* b4 = (const float*)d_in[15];

    const int total  = in_sizes[0];        // 12,582,912 floats
    const int nvec   = total / 4;          // 3,145,728 float4s
    const int blocks = total / 4096;       // 3072 blocks: one (n,c) slice each

    eb_fused<<<blocks, 256, 0, stream>>>(
        x, cb, m0, b0, f0, m1, b1, f1, m2, b2, f2, m3, b3_, f3, m4, b4,
        (float*)d_out, nvec);
}

// Round 5
// 181.640 us; speedup vs baseline: 1.1242x; 1.1242x over previous
//
#include <hip/hip_runtime.h>
#include <hip/hip_bf16.h>
#include <math.h>

// AdaptedEntropyBottleneck on MI355X.
// Shapes (fixed by setup_inputs): x [16,192,64,64] fp32, codebook [64] fp32 sorted,
// MLP params per channel: 1->3->3->3->3->1 with softplus(weights), tanh gates.
// Outputs: y_hat [N,C,H,W] then lik [N,C,H,W], concatenated flat in d_out (fp32).
//
// v5: split kernels again (v4 fusion made the pass VALU-bound: 16x redundant
// table build = ~half the VALU work, VALUBusy 80%).
//   - build_table_fast: ONE BLOCK PER CHANNEL (192 blocks x 128 threads,
//     one (k,side) chain per thread). v3's build_table had 48 workgroups ->
//     2% occupancy, latency-bound chain on 19% of CUs (74.6 us profiled).
//     Now all CUs run one ~1-2us chain in parallel, params wave-uniform.
//   - eb_main: round-3 version verbatim (register-pivot searchsorted,
//     3 LDS levels, y_hat from tie-break registers, 2048 elems/block).

#define CCH 192
#define KCB 64

typedef float f32x4 __attribute__((ext_vector_type(4)));

__device__ __forceinline__ float softplusf_(float x) {
    // jax.nn.softplus = logaddexp(x, 0) = max(x,0) + log1p(exp(-|x|))
    return fmaxf(x, 0.0f) + log1pf(expf(-fabsf(x)));
}
__device__ __forceinline__ float sigmoidf_(float x) {
    return 1.0f / (1.0f + expf(-x));
}

// One block per channel; thread t: side = t>>6 (0=lower,1=upper), k = t&63.
// Per-side arithmetic identical to the original build_table (same accumulation
// order), so numerics are unchanged.
__global__ __launch_bounds__(128) void build_table_fast(
        const float* __restrict__ cb,
        const float* __restrict__ m0, const float* __restrict__ b0, const float* __restrict__ f0,
        const float* __restrict__ m1, const float* __restrict__ b1, const float* __restrict__ f1,
        const float* __restrict__ m2, const float* __restrict__ b2, const float* __restrict__ f2,
        const float* __restrict__ m3, const float* __restrict__ b3, const float* __restrict__ f3,
        const float* __restrict__ m4, const float* __restrict__ b4,
        float* __restrict__ table) {
    __shared__ float s_side[128];
    const int tid = threadIdx.x;
    const int c   = blockIdx.x;
    const int k   = tid & 63;

    const float v = cb[k] + ((tid < 64) ? -0.5f : 0.5f);

    float h0, h1, h2;
    {   // layer 0: (C,3,1) weights
        float z;
        z = softplusf_(m0[c * 3 + 0]) * v + b0[c * 3 + 0];
        z = z + tanhf(f0[c * 3 + 0]) * tanhf(z); h0 = z;
        z = softplusf_(m0[c * 3 + 1]) * v + b0[c * 3 + 1];
        z = z + tanhf(f0[c * 3 + 1]) * tanhf(z); h1 = z;
        z = softplusf_(m0[c * 3 + 2]) * v + b0[c * 3 + 2];
        z = z + tanhf(f0[c * 3 + 2]) * tanhf(z); h2 = z;
    }
    const float* Ms[3] = {m1, m2, m3};
    const float* Bs[3] = {b1, b2, b3};
    const float* Fs[3] = {f1, f2, f3};
    #pragma unroll
    for (int L = 0; L < 3; ++L) {
        const float* M = Ms[L];
        const float* B = Bs[L];
        const float* F = Fs[L];
        float n0, n1, n2;
        #pragma unroll
        for (int j = 0; j < 3; ++j) {
            float z = 0.0f;
            z += softplusf_(M[(c * 3 + j) * 3 + 0]) * h0;
            z += softplusf_(M[(c * 3 + j) * 3 + 1]) * h1;
            z += softplusf_(M[(c * 3 + j) * 3 + 2]) * h2;
            z += B[c * 3 + j];
            const float a = tanhf(F[c * 3 + j]);
            z = z + a * tanhf(z);
            if (j == 0) n0 = z; else if (j == 1) n1 = z; else n2 = z;
        }
        h0 = n0; h1 = n1; h2 = n2;
    }
    // layer 4: (C,1,3) weights, bias (C,1,1)
    float res = 0.0f;
    res += softplusf_(m4[c * 3 + 0]) * h0;
    res += softplusf_(m4[c * 3 + 1]) * h1;
    res += softplusf_(m4[c * 3 + 2]) * h2;
    res += b4[c];
    s_side[tid] = res;
    __syncthreads();

    if (tid < 64) {
        const float lower = s_side[tid];
        const float upper = s_side[tid + 64];
        const float s  = lower + upper;
        const float sg = (s > 0.0f) ? -1.0f : ((s < 0.0f) ? 1.0f : 0.0f);
        float lik = fabsf(sigmoidf_(sg * upper) - sigmoidf_(sg * lower));
        table[c * 64 + tid] = fmaxf(lik, 1e-9f);
    }
}

// Each block: 256 threads * 8 elems = 2048 consecutive elements.
// H*W = 4096 -> every block lies entirely within one (n,c) slice:
// c = (blockIdx.x >> 1) % 192, block-uniform.
__global__ __launch_bounds__(256) void eb_main(
        const float* __restrict__ x,
        const float* __restrict__ cb,
        const float* __restrict__ table,
        float* __restrict__ out,
        int nvec) {
    __shared__ float s_cb[KCB];
    __shared__ float s_lik[KCB];
    const int tid = threadIdx.x;
    const int c = (blockIdx.x >> 1) % CCH;
    if (tid < 64) {
        s_cb[tid] = cb[tid];
    } else if (tid < 128) {
        s_lik[tid - 64] = table[c * 64 + (tid - 64)];
    }
    __syncthreads();

    // Pivots for the first 3 binary-search levels (wave-uniform broadcast reads).
    // Level-1 mid is always 32; level-2 mids are {16,48}; level-3 mids {8,24,40,56}.
    const float p32 = s_cb[32];
    const float p16 = s_cb[16], p48 = s_cb[48];
    const float p8  = s_cb[8],  p24 = s_cb[24], p40 = s_cb[40], p56 = s_cb[56];

    const int base4 = blockIdx.x * 512;     // float4 base index for this block
    #pragma unroll
    for (int half = 0; half < 2; ++half) {
        const int e4 = base4 + half * 256 + tid;   // float4 index
        if (e4 >= nvec) break;
        const f32x4 xv = ((const f32x4*)x)[e4];

        float xs[4] = {xv.x, xv.y, xv.z, xv.w};
        float ys[4], ls[4];
        #pragma unroll
        for (int q = 0; q < 4; ++q) {
            const float xx = xs[q];
            // searchsorted(cb, xx, side='left'): identical mid sequence to the
            // canonical 6-step loop, first 3 levels resolved from registers.
            const bool c1 = p32 < xx;
            const float v2 = c1 ? p48 : p16;
            const bool c2 = v2 < xx;
            const float v3 = c1 ? (c2 ? p56 : p40) : (c2 ? p24 : p8);
            const bool c3 = v3 < xx;

            int lo = c1 ? 33 : 0;
            int hi = c1 ? 64 : 32;
            const int m2i = c1 ? 48 : 16;
            lo = c2 ? (m2i + 1) : lo;
            hi = c2 ? hi : m2i;
            const int m3i = 8 + 16 * ((c1 ? 2 : 0) + (c2 ? 1 : 0));
            lo = c3 ? (m3i + 1) : lo;
            hi = c3 ? hi : m3i;

            #pragma unroll
            for (int it = 0; it < 3; ++it) {
                const int mid = (lo + hi) >> 1;
                if (s_cb[mid] < xx) lo = mid + 1; else hi = mid;
            }
            const int i  = lo;                       // insertion point in [0,64]
            int il = i - 1; il = (il < 0) ? 0 : il;
            const int ih = (i > 63) ? 63 : i;
            const float cl = s_cb[il];
            const float ch = s_cb[ih];
            // reference tie-break: pick hi iff |cb[hi]-x| < |cb[lo]-x| (strict)
            const bool pick_hi = fabsf(ch - xx) < fabsf(cl - xx);
            ys[q] = pick_hi ? ch : cl;               // y_hat from registers
            ls[q] = s_lik[pick_hi ? ih : il];
        }

        f32x4 yo;  yo.x  = ys[0]; yo.y  = ys[1]; yo.z  = ys[2]; yo.w  = ys[3];
        f32x4 lo4; lo4.x = ls[0]; lo4.y = ls[1]; lo4.z = ls[2]; lo4.w = ls[3];
        ((f32x4*)out)[e4]        = yo;
        ((f32x4*)out)[nvec + e4] = lo4;
    }
}

extern "C" void kernel_launch(void* const* d_in, const int* in_sizes, int n_in,
                              void* d_out, int out_size, void* d_ws, size_t ws_size,
                              hipStream_t stream) {
    // setup_inputs dict order:
    // 0:x 1:codebook 2:m0 3:b0 4:f0 5:m1 6:b1 7:f1 8:m2 9:b2 10:f2
    // 11:m3 12:b3 13:f3 14:m4 15:b4
    const float* x  = (const float*)d_in[0];
    const float* cb = (const float*)d_in[1];
    const float* m0 = (const float*)d_in[2];
    const float* b0 = (const float*)d_in[3];
    const float* f0 = (const float*)d_in[4];
    const float* m1 = (const float*)d_in[5];
    const float* b1 = (const float*)d_in[6];
    const float* f1 = (const float*)d_in[7];
    const float* m2 = (const float*)d_in[8];
    const float* b2 = (const float*)d_in[9];
    const float* f2 = (const float*)d_in[10];
    const float* m3 = (const float*)d_in[11];
    const float* b3_ = (const float*)d_in[12];
    const float* f3 = (const float*)d_in[13];
    const float* m4 = (const float*)d_in[14];
    const float* b4 = (const float*)d_in[15];

    float* table = (float*)d_ws;   // 12288 floats = 48 KB

    build_table_fast<<<CCH, 128, 0, stream>>>(
        cb, m0, b0, f0, m1, b1, f1, m2, b2, f2, m3, b3_, f3, m4, b4, table);

    const int total = in_sizes[0];         // 12,582,912 floats
    const int nvec  = total / 4;           // 3,145,728 float4s
    const int blocks = (nvec + 511) / 512; // 6,144 blocks (2048 elems/block)
    eb_main<<<blocks, 256, 0, stream>>>(x, cb, table, (float*)d_out, nvec);
}

// Round 6
// 179.133 us; speedup vs baseline: 1.1400x; 1.0140x over previous
//
#include <hip/hip_runtime.h>
#include <hip/hip_bf16.h>
#include <math.h>

// AdaptedEntropyBottleneck on MI355X.
// Shapes: x [16,192,64,64] fp32, codebook [64] fp32 sorted, per-channel MLP
// 1->3->3->3->3->1 with softplus weights + tanh gates.
// Outputs: y_hat then lik, concatenated flat fp32 in d_out.
//
// v6: exact uniform-grid LUT replaces the per-element binary search.
//  - build_all (200 blocks x 128): blocks 0..191 build the per-channel
//    64-entry lik table (same op order as reference chain -> same numerics);
//    blocks 192..199 build a 2048-bin uint8 LUT over [cb[0], cb[63]]:
//    LUT[b] = nearest index at bin start (exact reference search, 1e-4 guard
//    margin >> fp slop); bins whose window spans >=2 nearest-boundaries are
//    flagged 255 (expected ~1-2 bins) -> exact slow path in eb_main.
//    Monotonicity of nearest-index in x guarantees the true answer for a
//    clean bin is in {a, a+1}; the strict closer-compare between them is
//    exactly the reference tie-break. Bit-exact semantics.
//  - eb_main: per element ~13 VALU + 3 LDS ops (LUT u8 -> two parallel
//    ds_read_b64 of packed (cb,lik) -> select), serial LDS depth 3, vs the
//    old search's ~45 VALU + 6 LDS at depth 5 (VALUBusy was 80% in r4).

#define CCH 192
#define KCB 64
#define NBIN 2048

typedef float f32x4 __attribute__((ext_vector_type(4)));
typedef float f32x2 __attribute__((ext_vector_type(2)));

__device__ __forceinline__ float softplusf_(float x) {
    // jax.nn.softplus = logaddexp(x, 0) = max(x,0) + log1p(exp(-|x|))
    return fmaxf(x, 0.0f) + log1pf(expf(-fabsf(x)));
}
__device__ __forceinline__ float sigmoidf_(float x) {
    return 1.0f / (1.0f + expf(-x));
}

// Exact reference nearest-codebook: searchsorted(left) + strict-closer tie-break.
__device__ __forceinline__ int nearest_exact(const float* cb, float x) {
    int lo = 0, hi = 64;
    #pragma unroll
    for (int it = 0; it < 6; ++it) {
        const int mid = (lo + hi) >> 1;
        if (cb[mid] < x) lo = mid + 1; else hi = mid;
    }
    const int i  = lo;                 // insertion point in [0,64]
    int il = i - 1; il = (il < 0) ? 0 : il;
    const int ih = (i > 63) ? 63 : i;
    return (fabsf(cb[ih] - x) < fabsf(cb[il] - x)) ? ih : il;
}

// blocks 0..191: per-channel lik table (thread t: side=t>>6, k=t&63).
// blocks 192..199: uint8 nearest-LUT, 256 bins per block (2 per thread).
__global__ __launch_bounds__(128) void build_all(
        const float* __restrict__ cb,
        const float* __restrict__ m0, const float* __restrict__ b0, const float* __restrict__ f0,
        const float* __restrict__ m1, const float* __restrict__ b1, const float* __restrict__ f1,
        const float* __restrict__ m2, const float* __restrict__ b2, const float* __restrict__ f2,
        const float* __restrict__ m3, const float* __restrict__ b3, const float* __restrict__ f3,
        const float* __restrict__ m4, const float* __restrict__ b4,
        float* __restrict__ table, unsigned char* __restrict__ lut) {
    __shared__ float s_cb[KCB];
    __shared__ float s_side[128];
    const int tid = threadIdx.x;
    if (tid < 64) s_cb[tid] = cb[tid];
    __syncthreads();

    if (blockIdx.x < CCH) {
        const int c = blockIdx.x;
        const int k = tid & 63;
        const float v = s_cb[k] + ((tid < 64) ? -0.5f : 0.5f);

        float h0, h1, h2;
        {   // layer 0: (C,3,1) weights
            float z;
            z = softplusf_(m0[c * 3 + 0]) * v + b0[c * 3 + 0];
            z = z + tanhf(f0[c * 3 + 0]) * tanhf(z); h0 = z;
            z = softplusf_(m0[c * 3 + 1]) * v + b0[c * 3 + 1];
            z = z + tanhf(f0[c * 3 + 1]) * tanhf(z); h1 = z;
            z = softplusf_(m0[c * 3 + 2]) * v + b0[c * 3 + 2];
            z = z + tanhf(f0[c * 3 + 2]) * tanhf(z); h2 = z;
        }
        const float* Ms[3] = {m1, m2, m3};
        const float* Bs[3] = {b1, b2, b3};
        const float* Fs[3] = {f1, f2, f3};
        #pragma unroll
        for (int L = 0; L < 3; ++L) {
            const float* M = Ms[L];
            const float* B = Bs[L];
            const float* F = Fs[L];
            float n0, n1, n2;
            #pragma unroll
            for (int j = 0; j < 3; ++j) {
                float z = 0.0f;
                z += softplusf_(M[(c * 3 + j) * 3 + 0]) * h0;
                z += softplusf_(M[(c * 3 + j) * 3 + 1]) * h1;
                z += softplusf_(M[(c * 3 + j) * 3 + 2]) * h2;
                z += B[c * 3 + j];
                const float a = tanhf(F[c * 3 + j]);
                z = z + a * tanhf(z);
                if (j == 0) n0 = z; else if (j == 1) n1 = z; else n2 = z;
            }
            h0 = n0; h1 = n1; h2 = n2;
        }
        float res = 0.0f;
        res += softplusf_(m4[c * 3 + 0]) * h0;
        res += softplusf_(m4[c * 3 + 1]) * h1;
        res += softplusf_(m4[c * 3 + 2]) * h2;
        res += b4[c];
        s_side[tid] = res;
        __syncthreads();

        if (tid < 64) {
            const float lower = s_side[tid];
            const float upper = s_side[tid + 64];
            const float s  = lower + upper;
            const float sg = (s > 0.0f) ? -1.0f : ((s < 0.0f) ? 1.0f : 0.0f);
            float lik = fabsf(sigmoidf_(sg * upper) - sigmoidf_(sg * lower));
            table[c * 64 + tid] = fmaxf(lik, 1e-9f);
        }
    } else {
        // LUT blocks
        const float cbmin = s_cb[0], cbmax = s_cb[63];
        const float w = (cbmax - cbmin) / (float)NBIN;
        const float margin = 1e-4f;    // >> fp bin-rounding slop (~2.4e-6)
        const int bb = (blockIdx.x - CCH) * 256;
        #pragma unroll
        for (int r = 0; r < 2; ++r) {
            const int b = bb + r * 128 + tid;
            const float xs = cbmin + w * (float)b;
            const int ns = nearest_exact(s_cb, xs - margin);
            const int ne = nearest_exact(s_cb, xs + w + margin);
            lut[b] = (ne - ns <= 1) ? (unsigned char)ns : (unsigned char)255;
        }
    }
}

// Each block: 256 threads * 8 elems = 2048 consecutive elements.
// H*W = 4096 -> block lies in one (n,c) slice: c = (blockIdx.x>>1) % 192.
__global__ __launch_bounds__(256) void eb_main(
        const float* __restrict__ x,
        const float* __restrict__ cb,
        const float* __restrict__ table,
        const unsigned char* __restrict__ lut,
        float* __restrict__ out,
        int nvec) {
    __shared__ float s_cb[KCB];            // for rare exact slow path
    __shared__ f32x2 s_pair[KCB];          // {codebook value, lik}
    __shared__ unsigned char s_lut[NBIN];

    const int tid = threadIdx.x;
    const int c = (blockIdx.x >> 1) % CCH;

    // stage LUT: 256 threads x 8 bytes = 2048 B
    ((unsigned long long*)s_lut)[tid] = ((const unsigned long long*)lut)[tid];
    if (tid < 64) {
        const float cv = cb[tid];
        s_cb[tid] = cv;
        f32x2 p; p.x = cv; p.y = table[c * 64 + tid];
        s_pair[tid] = p;
    }
    __syncthreads();

    const float cbmin = s_cb[0];
    const float scale = (float)NBIN / (s_cb[63] - cbmin);

    const int base4 = blockIdx.x * 512;     // float4 base index for this block
    #pragma unroll
    for (int half = 0; half < 2; ++half) {
        const int e4 = base4 + half * 256 + tid;
        if (e4 >= nvec) break;
        const f32x4 xv = ((const f32x4*)x)[e4];

        float xs_[4] = {xv.x, xv.y, xv.z, xv.w};
        float ys[4], ls[4];
        #pragma unroll
        for (int q = 0; q < 4; ++q) {
            const float xx = xs_[q];
            int bin = (int)((xx - cbmin) * scale);
            bin = bin < 0 ? 0 : (bin > NBIN - 1 ? NBIN - 1 : bin);
            int a = s_lut[bin];
            int idx_l, idx_h;
            if (__builtin_expect(a == 255, 0)) {
                // exact slow path (expected ~0.1% of elements)
                const int nn = nearest_exact(s_cb, xx);
                idx_l = nn; idx_h = nn;
            } else {
                idx_l = a;
                idx_h = (a + 1 > 63) ? 63 : a + 1;
            }
            const f32x2 pl = s_pair[idx_l];
            const f32x2 ph = s_pair[idx_h];
            // reference tie-break: pick hi iff strictly closer
            const bool pick_hi = fabsf(ph.x - xx) < fabsf(pl.x - xx);
            ys[q] = pick_hi ? ph.x : pl.x;
            ls[q] = pick_hi ? ph.y : pl.y;
        }

        f32x4 yo;  yo.x  = ys[0]; yo.y  = ys[1]; yo.z  = ys[2]; yo.w  = ys[3];
        f32x4 lo4; lo4.x = ls[0]; lo4.y = ls[1]; lo4.z = ls[2]; lo4.w = ls[3];
        ((f32x4*)out)[e4]        = yo;
        ((f32x4*)out)[nvec + e4] = lo4;
    }
}

extern "C" void kernel_launch(void* const* d_in, const int* in_sizes, int n_in,
                              void* d_out, int out_size, void* d_ws, size_t ws_size,
                              hipStream_t stream) {
    // setup_inputs dict order:
    // 0:x 1:codebook 2:m0 3:b0 4:f0 5:m1 6:b1 7:f1 8:m2 9:b2 10:f2
    // 11:m3 12:b3 13:f3 14:m4 15:b4
    const float* x  = (const float*)d_in[0];
    const float* cb = (const float*)d_in[1];
    const float* m0 = (const float*)d_in[2];
    const float* b0 = (const float*)d_in[3];
    const float* f0 = (const float*)d_in[4];
    const float* m1 = (const float*)d_in[5];
    const float* b1 = (const float*)d_in[6];
    const float* f1 = (const float*)d_in[7];
    const float* m2 = (const float*)d_in[8];
    const float* b2 = (const float*)d_in[9];
    const float* f2 = (const float*)d_in[10];
    const float* m3 = (const float*)d_in[11];
    const float* b3_ = (const float*)d_in[12];
    const float* f3 = (const float*)d_in[13];
    const float* m4 = (const float*)d_in[14];
    const float* b4 = (const float*)d_in[15];

    float* table = (float*)d_ws;                         // 12288 f32 = 48 KB
    unsigned char* lut = (unsigned char*)d_ws + 49152;   // 2048 u8

    build_all<<<CCH + 8, 128, 0, stream>>>(
        cb, m0, b0, f0, m1, b1, f1, m2, b2, f2, m3, b3_, f3, m4, b4,
        table, lut);

    const int total = in_sizes[0];         // 12,582,912 floats
    const int nvec  = total / 4;           // 3,145,728 float4s
    const int blocks = (nvec + 511) / 512; // 6,144 blocks (2048 elems/block)
    eb_main<<<blocks, 256, 0, stream>>>(x, cb, table, lut, (float*)d_out, nvec);
}